// Round 10
// baseline (157.865 us; speedup 1.0000x reference)
//
#include <hip/hip_runtime.h>
#include <math.h>

#define N_SQ   7          // 7 squarings -> A^128; Frobenius -> trace(A^256)
#define INV_P  (1.0f / 256.0f)
#define EPS_F  1e-20f
#define PH     72         // f16 pitch for staged 64-row planes
#define PQ     67         // f32 pitch for Q1 transpose buffer

typedef _Float16 h2    __attribute__((ext_vector_type(2)));
typedef _Float16 f16x8 __attribute__((ext_vector_type(8)));
typedef float    f32x4 __attribute__((ext_vector_type(4)));

__device__ inline float cdot2(h2 a, h2 b, float c) {
#if __has_builtin(__builtin_amdgcn_fdot2)
    return __builtin_amdgcn_fdot2(a, b, c, false);
#else
    return c + (float)a.x * (float)b.x + (float)a.y * (float)b.y;
#endif
}
__device__ inline h2 bch2(unsigned int x) { return __builtin_bit_cast(h2, x); }
__device__ inline h2 bch2f(float x)       { return __builtin_bit_cast(h2, x); }
__device__ inline float bcf(h2 x)         { return __builtin_bit_cast(float, x); }

// ws layout: res_final [0, 36864) floats; counters int[8] at byte 147456.

__global__ __launch_bounds__(1024) void ista_fused_kernel(
    const float* __restrict__ Dre, const float* __restrict__ Dim,
    const float* __restrict__ Cre, const float* __restrict__ Cim,
    float* __restrict__ out, float* __restrict__ ws, int* __restrict__ cnt)
{
    const int bs = blockIdx.x;     // 0..71
    const int bb = bs / 9;         // batch index
    const int t  = threadIdx.x;    // 0..1023
    const int wv = t >> 6;         // wave 0..15
    const int ln = t & 63;         // lane
    const int c16 = ln & 15;       // MFMA col / row-select
    const int qd  = ln >> 4;       // MFMA quad
    const float* __restrict__ dre = Dre + (size_t)bs * 32768;
    const float* __restrict__ dim = Dim + (size_t)bs * 32768;

    // uBuf aliases:
    //  C/D: ShRe f16[64*PH] (fl [0,2304)) | ShIm (fl [2304,4608)) | Q1 fl [4608,8896)
    //  B:   sDh fl [0,2048)
    //  E:   sUp fl [0,2048) | sHu fl [2048,2176) | sResH f16 (fl [2176,2432)) | sW fl [2432,4480)
    __shared__ __align__(16) float uBuf[9216];
    _Float16* ShRe = (_Float16*)uBuf;
    _Float16* ShIm = (_Float16*)uBuf + 64 * PH;
    float*    Q1   = uBuf + 4608;
    float*    sDh  = uBuf;
    float*    sUp  = uBuf;
    float*    sHu  = uBuf + 2048;
    _Float16* sResH = (_Float16*)(uBuf + 2176);
    float*    sW   = uBuf + 2432;
    __shared__ __align__(16) float s_r[128];
    __shared__ float s_red[32];
    __shared__ float s_scal[8];  // 0=gamma 1=theta 2=max|Dhr| 3=E(log) 4=1/c 5=lo 6=hi 7=norm2
    __shared__ int   sFlag;

    // ---------------- Phase A: r = vec(C^T) ----------------
    if (t < 64) {
        int i = t >> 3, j = t & 7;
        s_r[2 * t]     = Cre[bs * 64 + j * 8 + i];
        s_r[2 * t + 1] = Cim[bs * 64 + j * 8 + i];
    }
    __syncthreads();

    // ---------------- Phase B: Dhr partials + dV tile (m-half per thread) ----------------
    const int g5 = t & 511;        // g for B/E-w phases
    const int mh = t >> 9;         // m-half: 0 or 1
    h2 dV[32];                     // D[32mh+k][g5] packed f16  (32 VGPRs)
    float dhr_re = 0.f, dhr_im = 0.f;
    {
        const int mb = mh << 5;
        #pragma unroll
        for (int k = 0; k < 32; ++k) {
            int m = mb + k;
            float ar = dre[m * 512 + g5], ai = dim[m * 512 + g5];
            dV[k] = h2{(_Float16)ar, (_Float16)ai};
            float rr = s_r[2 * m], ri = s_r[2 * m + 1];
            dhr_re += ar * rr + ai * ri;
            dhr_im += ar * ri - ai * rr;
        }
    }
    sDh[2 * t] = dhr_re; sDh[2 * t + 1] = dhr_im;
    __syncthreads();
    if (t < 512) {
        dhr_re = sDh[2 * t] + sDh[2 * (t + 512)];
        dhr_im = sDh[2 * t + 1] + sDh[2 * (t + 512) + 1];
        float sv = dhr_re * dhr_re;
        float mv = sqrtf(dhr_re * dhr_re + dhr_im * dhr_im);
        for (int off = 32; off; off >>= 1) {
            sv += __shfl_down(sv, off, 64);
            mv = fmaxf(mv, __shfl_down(mv, off, 64));
        }
        if (ln == 0) { s_red[wv] = sv; s_red[16 + wv] = mv; }
    }
    __syncthreads();
    if (t == 0) {
        float ss = 0.f, mm = 0.f;
        for (int k = 0; k < 8; ++k) { ss += s_red[k]; mm = fmaxf(mm, s_red[16 + k]); }
        s_scal[7] = ss; s_scal[2] = mm;
    }
    __syncthreads();
    float res_g = (t < 512) ? dhr_re / (sqrtf(s_scal[7]) + EPS_F) : 0.f;

    // ---------------- MFMA tile ownership: wave wv owns tile wv of 4x4 ----------------
    const int I = wv >> 2, J = wv & 3;

    auto epilogue = [&](f32x4 P, f32x4 Qa, bool first, bool last) {
        #pragma unroll
        for (int r = 0; r < 4; ++r)
            Q1[(I * 16 + qd * 4 + r) * PQ + J * 16 + c16] = Qa[r];
        float dv = 0.f;
        if (I == J) {
            #pragma unroll
            for (int r = 0; r < 4; ++r) if (qd * 4 + r == c16) dv = fmaxf(dv, fabsf(P[r]));
        }
        for (int off = 32; off; off >>= 1) dv = fmaxf(dv, __shfl_down(dv, off, 64));
        if (ln == 0) s_red[wv] = dv;
        __syncthreads();
        if (t == 0) {
            float m = 0.f;
            for (int k = 0; k < 16; ++k) m = fmaxf(m, s_red[k]);
            s_scal[3] = first ? logf(m) : 2.f * s_scal[3] + logf(m);
            s_scal[4] = 1.f / m;
        }
        __syncthreads();
        float ic = s_scal[4];
        float ci[4];
        #pragma unroll
        for (int r = 0; r < 4; ++r)
            ci[r] = Qa[r] - Q1[(J * 16 + c16) * PQ + I * 16 + qd * 4 + r];
        if (!last) {
            #pragma unroll
            for (int r = 0; r < 4; ++r) {
                ShRe[(I * 16 + qd * 4 + r) * PH + J * 16 + c16] = (_Float16)(P[r] * ic);
                ShIm[(I * 16 + qd * 4 + r) * PH + J * 16 + c16] = (_Float16)(ci[r] * ic);
            }
            __syncthreads();
        } else {
            float fr = 0.f;
            #pragma unroll
            for (int r = 0; r < 4; ++r) fr += P[r] * P[r] + ci[r] * ci[r];
            fr *= ic * ic;
            for (int off = 32; off; off >>= 1) fr += __shfl_down(fr, off, 64);
            if (ln == 0) s_red[wv] = fr;
            __syncthreads();
            if (t == 0) {
                float fsum = 0.f;
                for (int k = 0; k < 16; ++k) fsum += s_red[k];
                float loglam = (2.f * s_scal[3] + logf(fsum)) * INV_P;
                float gamma = expf(-loglam);
                s_scal[0] = gamma;
                s_scal[1] = 0.5f * s_scal[2] * gamma;
            }
            __syncthreads();
        }
    };

    // ---------------- Phase C: Gram via MFMA (8 chunks, no staging loop) ----------------
    h2 du_re[16], du_im[16];   // row ln, g in [32wv, 32wv+32)  (32 VGPRs)
    f32x4 gP = {0.f, 0.f, 0.f, 0.f}, gQ = {0.f, 0.f, 0.f, 0.f};
    {
        const int srow = t >> 4;          // 0..63
        const int scb  = (t & 15) * 4;    // col base in chunk
        float4 pr0 = *(const float4*)&dre[srow * 512 + scb];
        float4 pi0 = *(const float4*)&dim[srow * 512 + scb];
        const int myc = wv >> 1, cb = (wv & 1) * 32;
        for (int ch = 0; ch < 8; ++ch) {
            *(h2*)&ShRe[srow * PH + scb]     = h2{(_Float16)pr0.x, (_Float16)pr0.y};
            *(h2*)&ShRe[srow * PH + scb + 2] = h2{(_Float16)pr0.z, (_Float16)pr0.w};
            *(h2*)&ShIm[srow * PH + scb]     = h2{(_Float16)pi0.x, (_Float16)pi0.y};
            *(h2*)&ShIm[srow * PH + scb + 2] = h2{(_Float16)pi0.z, (_Float16)pi0.w};
            if (ch < 7) {
                int gc = (ch + 1) * 64;
                pr0 = *(const float4*)&dre[srow * 512 + gc + scb];
                pi0 = *(const float4*)&dim[srow * 512 + gc + scb];
            }
            __syncthreads();
            #pragma unroll
            for (int ks = 0; ks < 64; ks += 32) {
                f16x8 arI = *(const f16x8*)&ShRe[(I * 16 + c16) * PH + ks + qd * 8];
                f16x8 aiI = *(const f16x8*)&ShIm[(I * 16 + c16) * PH + ks + qd * 8];
                f16x8 arJ = *(const f16x8*)&ShRe[(J * 16 + c16) * PH + ks + qd * 8];
                f16x8 aiJ = *(const f16x8*)&ShIm[(J * 16 + c16) * PH + ks + qd * 8];
                gP = __builtin_amdgcn_mfma_f32_16x16x32_f16(arI, arJ, gP, 0, 0, 0);
                gP = __builtin_amdgcn_mfma_f32_16x16x32_f16(aiI, aiJ, gP, 0, 0, 0);
                gQ = __builtin_amdgcn_mfma_f32_16x16x32_f16(aiI, arJ, gQ, 0, 0, 0);
            }
            if (ch == myc) {
                #pragma unroll
                for (int c = 0; c < 4; ++c) {
                    uint4 aw = *(const uint4*)&ShRe[ln * PH + cb + 8 * c];
                    du_re[4 * c + 0] = bch2(aw.x); du_re[4 * c + 1] = bch2(aw.y);
                    du_re[4 * c + 2] = bch2(aw.z); du_re[4 * c + 3] = bch2(aw.w);
                    uint4 bw = *(const uint4*)&ShIm[ln * PH + cb + 8 * c];
                    du_im[4 * c + 0] = bch2(bw.x); du_im[4 * c + 1] = bch2(bw.y);
                    du_im[4 * c + 2] = bch2(bw.z); du_im[4 * c + 3] = bch2(bw.w);
                }
            }
            __syncthreads();
        }
    }
    epilogue(gP, gQ, true, false);

    // ---------------- Phase D: 7 scaled squarings via MFMA ----------------
    for (int sq = 0; sq < N_SQ; ++sq) {
        f32x4 P = {0.f, 0.f, 0.f, 0.f}, Qa = {0.f, 0.f, 0.f, 0.f};
        #pragma unroll
        for (int ks = 0; ks < 64; ks += 32) {
            f16x8 arI = *(const f16x8*)&ShRe[(I * 16 + c16) * PH + ks + qd * 8];
            f16x8 aiI = *(const f16x8*)&ShIm[(I * 16 + c16) * PH + ks + qd * 8];
            f16x8 arJ = *(const f16x8*)&ShRe[(J * 16 + c16) * PH + ks + qd * 8];
            f16x8 aiJ = *(const f16x8*)&ShIm[(J * 16 + c16) * PH + ks + qd * 8];
            P  = __builtin_amdgcn_mfma_f32_16x16x32_f16(arI, arJ, P, 0, 0, 0);
            P  = __builtin_amdgcn_mfma_f32_16x16x32_f16(aiI, aiJ, P, 0, 0, 0);
            Qa = __builtin_amdgcn_mfma_f32_16x16x32_f16(aiI, arJ, Qa, 0, 0, 0);
        }
        epilogue(P, Qa, false, sq == N_SQ - 1);
    }

    // ---------------- Phase E: 16 ISTA layers (register tiles, 4 barriers/layer) ----------------
    const float gamma = s_scal[0];
    const float theta = s_scal[1];
    float* out_init = out + 40960 + (size_t)bs * 8192;
    const int resh_base = 32 * wv;     // f16 elements, g-slice of this wave

    for (int l = 0; l < 16; ++l) {
        if (t < 512) sResH[t] = (_Float16)res_g;
        __syncthreads();
        // u-partial: m = ln over g-slice [32wv, 32wv+32)
        float upR = 0.f, upI = 0.f;
        #pragma unroll
        for (int c = 0; c < 4; ++c) {
            uint4 rw = *(const uint4*)&sResH[resh_base + 8 * c];
            h2 r0 = bch2(rw.x), r1 = bch2(rw.y), r2 = bch2(rw.z), r3 = bch2(rw.w);
            upR = cdot2(du_re[4 * c + 0], r0, upR);  upI = cdot2(du_im[4 * c + 0], r0, upI);
            upR = cdot2(du_re[4 * c + 1], r1, upR);  upI = cdot2(du_im[4 * c + 1], r1, upI);
            upR = cdot2(du_re[4 * c + 2], r2, upR);  upI = cdot2(du_im[4 * c + 2], r2, upI);
            upR = cdot2(du_re[4 * c + 3], r3, upR);  upI = cdot2(du_im[4 * c + 3], r3, upI);
        }
        *(float2*)&sUp[wv * 128 + 2 * ln] = make_float2(upR, upI);
        __syncthreads();
        // combine u over 16 slices: t<64, m=t
        if (t < 64) {
            float ufR = 0.f, ufI = 0.f;
            #pragma unroll
            for (int p = 0; p < 16; ++p) {
                float2 q = *(const float2*)&sUp[p * 128 + 2 * t];
                ufR += q.x; ufI += q.y;
            }
            h2 hu1 = h2{(_Float16)ufR, (_Float16)ufI};
            h2 hu2 = h2{(_Float16)ufI, (_Float16)(-ufR)};
            *(float2*)&sHu[2 * t] = make_float2(bcf(hu1), bcf(hu2));
        }
        __syncthreads();
        // w-partial: g = g5, m in [32mh, 32mh+32)
        float wR = 0.f, wI = 0.f;
        {
            const int pb = 16 * mh;
            #pragma unroll
            for (int j = 0; j < 16; ++j) {
                float4 hq = *(const float4*)&sHu[4 * (pb + j)];
                wR = cdot2(dV[2 * j],     bch2f(hq.x), wR);
                wI = cdot2(dV[2 * j],     bch2f(hq.y), wI);
                wR = cdot2(dV[2 * j + 1], bch2f(hq.z), wR);
                wI = cdot2(dV[2 * j + 1], bch2f(hq.w), wI);
            }
        }
        *(float2*)&sW[mh * 1024 + 2 * g5] = make_float2(wR, wI);
        __syncthreads();
        if (t < 512) {
            float2 wa = *(const float2*)&sW[2 * t];
            float2 wb = *(const float2*)&sW[1024 + 2 * t];
            float sre = res_g + gamma * (dhr_re - (wa.x + wb.x));
            float sim = gamma * (dhr_im - (wa.y + wb.y));
            float mag = sqrtf(sre * sre + sim * sim);
            res_g = fmaxf(mag - theta, 0.f);
            out_init[l * 512 + t] = res_g;
        }
    }

    // ---------------- Phase F: per-(b,s) epilogue ----------------
    if (t < 512) {
        float mn = res_g, mx = res_g;
        for (int off = 32; off; off >>= 1) {
            mn = fminf(mn, __shfl_down(mn, off, 64));
            mx = fmaxf(mx, __shfl_down(mx, off, 64));
        }
        if (ln == 0) { s_red[wv] = mn; s_red[16 + wv] = mx; }
    }
    __syncthreads();
    if (t == 0) {
        float a = s_red[0], b2 = s_red[16];
        for (int k = 1; k < 8; ++k) { a = fminf(a, s_red[k]); b2 = fmaxf(b2, s_red[16 + k]); }
        s_scal[5] = a; s_scal[6] = b2;
    }
    __syncthreads();
    if (t < 512) {
        out[bs * 512 + t] = (res_g - s_scal[5]) / (s_scal[6] - s_scal[5] + EPS_F);
        ws[bs * 512 + t] = res_g;
    }
    __threadfence();
    __syncthreads();

    // ---------------- Fused ave: last block per batch computes result_ave ----------------
    if (t == 0) {
        int old = __hip_atomic_fetch_add(&cnt[bb], 1, __ATOMIC_ACQ_REL, __HIP_MEMORY_SCOPE_AGENT);
        sFlag = (old == 8) ? 1 : 0;
    }
    __syncthreads();
    if (sFlag) {
        __threadfence();
        float acc = 0.f;
        if (t < 512) {
            #pragma unroll
            for (int s = 0; s < 9; ++s) acc += ws[(bb * 9 + s) * 512 + t];
            acc *= (1.f / 9.f);
            float mn = acc, mx = acc;
            for (int off = 32; off; off >>= 1) {
                mn = fminf(mn, __shfl_down(mn, off, 64));
                mx = fmaxf(mx, __shfl_down(mx, off, 64));
            }
            if (ln == 0) { s_red[wv] = mn; s_red[16 + wv] = mx; }
        }
        __syncthreads();
        if (t == 0) {
            float a = s_red[0], b2 = s_red[16];
            for (int k = 1; k < 8; ++k) { a = fminf(a, s_red[k]); b2 = fmaxf(b2, s_red[16 + k]); }
            s_scal[5] = a; s_scal[6] = b2;
        }
        __syncthreads();
        if (t < 512)
            out[36864 + bb * 512 + t] = (acc - s_scal[5]) / (s_scal[6] - s_scal[5] + EPS_F);
    }
}

extern "C" void kernel_launch(void* const* d_in, const int* in_sizes, int n_in,
                              void* d_out, int out_size, void* d_ws, size_t ws_size,
                              hipStream_t stream) {
    const float* Dre = (const float*)d_in[0];
    const float* Dim = (const float*)d_in[1];
    const float* Cre = (const float*)d_in[2];
    const float* Cim = (const float*)d_in[3];
    float* out = (float*)d_out;
    float* ws  = (float*)d_ws;
    int*   cnt = (int*)((char*)d_ws + 147456);

    hipMemsetAsync(cnt, 0, 8 * sizeof(int), stream);
    ista_fused_kernel<<<72, 1024, 0, stream>>>(Dre, Dim, Cre, Cim, out, ws, cnt);
}